// Round 8
// baseline (574.639 us; speedup 1.0000x reference)
//
#include <hip/hip_runtime.h>
#include <math.h>

// Problem constants
#define B_     64
#define N_TOK  196
#define C_     768
#define H_     12
#define D_     64
#define NN_    (N_TOK * N_TOK)     // 38416
#define M_     (B_ * N_TOK)        // 12544

static constexpr float kRbfScale = -0.0625f;  // -0.5 * 64^-0.5

typedef __attribute__((ext_vector_type(8))) short bf16x8;
typedef __attribute__((ext_vector_type(4))) float f32x4;

// bf16 round-to-nearest-even helpers
static __device__ __forceinline__ unsigned short f2b(float f) {
  unsigned int u = __float_as_uint(f);
  u += 0x7fffu + ((u >> 16) & 1u);
  return (unsigned short)(u >> 16);
}
static __device__ __forceinline__ float b2f(unsigned short h) {
  return __uint_as_float(((unsigned int)h) << 16);
}

// async global->LDS, 16B per lane, linear LDS dest (wave-uniform base + lane*16)
#define GLL(g, l)                                                       \
  __builtin_amdgcn_global_load_lds(                                     \
      (const __attribute__((address_space(1))) void*)(g),               \
      (__attribute__((address_space(3))) void*)(l), 16, 0, 0)

// ---------------------------------------------------------------------------
// Bias precompute: bias[h][i][j] = gelu(rpe_table[rpe_index[i][j]][h])
// Shared across all 64 batches -> compute once (1.84 MB, L2/L3-resident).
// ---------------------------------------------------------------------------
__global__ void bias_gelu_kernel(const float* __restrict__ rpe_table,
                                 const int* __restrict__ rpe_index,
                                 float* __restrict__ bias) {
  const int ij = blockIdx.x * 256 + threadIdx.x;
  if (ij >= NN_) return;
  const int idx = rpe_index[ij];
#pragma unroll
  for (int h = 0; h < H_; ++h) {
    const float r = rpe_table[idx * H_ + h];
    bias[h * NN_ + ij] = 0.5f * r * (1.0f + erff(r * 0.70710678118654752440f));
  }
}

// ---------------------------------------------------------------------------
// Split fp32 -> bf16 hi/lo (elementwise, float4-vectorized)
// ---------------------------------------------------------------------------
__global__ void split_x_kernel(const float* __restrict__ X,
                               unsigned short* __restrict__ Xh,
                               unsigned short* __restrict__ Xl, int n4) {
  const int i = blockIdx.x * 256 + threadIdx.x;
  if (i >= n4) return;
  const float4 v = reinterpret_cast<const float4*>(X)[i];
  ushort4 h, l;
  h.x = f2b(v.x); l.x = f2b(v.x - b2f(h.x));
  h.y = f2b(v.y); l.y = f2b(v.y - b2f(h.y));
  h.z = f2b(v.z); l.z = f2b(v.z - b2f(h.z));
  h.w = f2b(v.w); l.w = f2b(v.w - b2f(h.w));
  reinterpret_cast<ushort4*>(Xh)[i] = h;
  reinterpret_cast<ushort4*>(Xl)[i] = l;
}

// ---------------------------------------------------------------------------
// Transpose + split, 4 weights in one launch (blockIdx.z selects):
// W[k][n] fp32 -> WT_hi/WT_lo[n][k] bf16  (768x768 each).
// Output planes CONSECUTIVE: Th(z) = ThBase + z*2*C*C, Tl(z) = Th(z) + C*C.
// ---------------------------------------------------------------------------
__global__ void transpose_split4_kernel(
    const float* __restrict__ W0, const float* __restrict__ W1,
    const float* __restrict__ W2, const float* __restrict__ W3,
    unsigned short* __restrict__ ThBase) {
  const int z = blockIdx.z;
  const float* W = (z == 0) ? W0 : (z == 1) ? W1 : (z == 2) ? W2 : W3;
  const size_t wtn = (size_t)C_ * C_;
  unsigned short* Th = ThBase + (size_t)z * 2 * wtn;
  unsigned short* Tl = Th + wtn;

  __shared__ float t[32][33];
  const int bk = blockIdx.x * 32;  // k block
  const int bn = blockIdx.y * 32;  // n block
  const int lx = threadIdx.x & 31;
  const int ly = threadIdx.x >> 5;  // 0..7
#pragma unroll
  for (int r = ly; r < 32; r += 8) t[r][lx] = W[(size_t)(bk + r) * C_ + bn + lx];
  __syncthreads();
#pragma unroll
  for (int r = ly; r < 32; r += 8) {
    const float v = t[lx][r];  // = W[bk+lx][bn+r] -> WT[n=bn+r][k=bk+lx]
    const unsigned short h = f2b(v);
    Th[(size_t)(bn + r) * C_ + bk + lx] = h;
    Tl[(size_t)(bn + r) * C_ + bk + lx] = f2b(v - b2f(h));
  }
}

// ---------------------------------------------------------------------------
// bf16x4 MFMA GEMM, z-batched over weight/output planes:
//   C(z)[M,768] = A @ W(z) (+bias), z = blockIdx.z
//   W(z) = WBase + z*2*C*C (hi), +C*C (lo);  C(z) = CBase + z*M*C.
// 128x128 tile, BK=32, 4 waves each owning 64x64 (4x4 frags of 16x16x32).
// acc += Ah*Bh + Ah*Bl + Al*Bh + Al*Bl  (full 4-term split: products are
// exact in fp32 accumulate -> end-to-end ~1e-5 of the fp32 reference;
// tolerance-insurance, revert to 3-term once harness tolerance is known).
// LDS: 4 planes of [128 rows][4 slots x 16B], linear dest for global_load_lds
// (rule 21: dest must be wave_base + lane*16; chunk*1024 + (lane>>2)*64 +
// (lane&3)*16 == chunk*1024 + lane*16). Swizzle slot ^= (row>>1)&3 applied to
// the per-lane GLOBAL source; read applies the same XOR -> reads recover
// global[row][g] and the 16-lane quarter-wave lands on banks
// {0,16,4,20,8,24,12,28}x2 = 2-way aliasing (free, m136).
// NOTE: no min-waves in launch_bounds — (256,2) would cap VGPR at 128 and
// spill the 64-reg accumulator + 64-reg fragment set to scratch.
// ---------------------------------------------------------------------------
__global__ __launch_bounds__(256) void gemm_bf16x4_kernel(
    const unsigned short* __restrict__ Ah, const unsigned short* __restrict__ Al,
    const unsigned short* __restrict__ WBase, float* __restrict__ CBase,
    const float* __restrict__ bias) {
  __shared__ __align__(16) char lds[32768];
  char* const ldsAh = lds;
  char* const ldsAl = lds + 8192;
  char* const ldsBh = lds + 16384;
  char* const ldsBl = lds + 24576;

  const size_t wtn = (size_t)C_ * C_;
  const unsigned short* Bh = WBase + (size_t)blockIdx.z * 2 * wtn;
  const unsigned short* Bl = Bh + wtn;
  float* C = CBase + (size_t)blockIdx.z * M_ * C_;

  const int tid = threadIdx.x;
  const int lane = tid & 63;
  const int wv = tid >> 6;       // 0..3
  const int wr = wv >> 1;        // wave row 0..1
  const int wc = wv & 1;         // wave col 0..1
  const int m0 = blockIdx.x * 128;
  const int n0 = blockIdx.y * 128;

  // staging: wave wv owns chunks {2wv, 2wv+1}; chunk = 16 rows x 64B.
  const int chunk0 = wv * 2;
  const int chunk1 = wv * 2 + 1;
  size_t aoff0, aoff1, boff0, boff1;
  {
    const int r0 = chunk0 * 16 + (lane >> 2);
    const int r1 = chunk1 * 16 + (lane >> 2);
    const int s0 = (lane & 3) ^ ((r0 >> 1) & 3);
    const int s1 = (lane & 3) ^ ((r1 >> 1) & 3);
    aoff0 = (size_t)(m0 + r0) * C_ + s0 * 8;
    aoff1 = (size_t)(m0 + r1) * C_ + s1 * 8;
    boff0 = (size_t)(n0 + r0) * C_ + s0 * 8;
    boff1 = (size_t)(n0 + r1) * C_ + s1 * 8;
  }

  f32x4 acc[4][4];
#pragma unroll
  for (int mi = 0; mi < 4; ++mi)
#pragma unroll
    for (int ni = 0; ni < 4; ++ni) acc[mi][ni] = (f32x4){0.f, 0.f, 0.f, 0.f};

  const int rbase = lane & 15;                  // MFMA fragment row/col
  const int swzb = ((rbase >> 1) & 3) << 4;     // read-side XOR (bytes)
  const int colb = ((lane >> 4) * 16) ^ swzb;   // k-group byte offset

  for (int k0 = 0; k0 < C_; k0 += 32) {
    GLL(Ah + aoff0 + k0, ldsAh + chunk0 * 1024);
    GLL(Ah + aoff1 + k0, ldsAh + chunk1 * 1024);
    GLL(Al + aoff0 + k0, ldsAl + chunk0 * 1024);
    GLL(Al + aoff1 + k0, ldsAl + chunk1 * 1024);
    GLL(Bh + boff0 + k0, ldsBh + chunk0 * 1024);
    GLL(Bh + boff1 + k0, ldsBh + chunk1 * 1024);
    GLL(Bl + boff0 + k0, ldsBl + chunk0 * 1024);
    GLL(Bl + boff1 + k0, ldsBl + chunk1 * 1024);
    __syncthreads();  // compiler drains vmcnt(0) before s_barrier

    bf16x8 ah[4], al[4], bh[4], bl[4];
#pragma unroll
    for (int t = 0; t < 4; ++t) {
      const int ra = (wr * 64 + t * 16 + rbase) * 64 + colb;
      const int rb = (wc * 64 + t * 16 + rbase) * 64 + colb;
      ah[t] = *reinterpret_cast<const bf16x8*>(ldsAh + ra);
      al[t] = *reinterpret_cast<const bf16x8*>(ldsAl + ra);
      bh[t] = *reinterpret_cast<const bf16x8*>(ldsBh + rb);
      bl[t] = *reinterpret_cast<const bf16x8*>(ldsBl + rb);
    }
#pragma unroll
    for (int mi = 0; mi < 4; ++mi)
#pragma unroll
      for (int ni = 0; ni < 4; ++ni) {
        acc[mi][ni] = __builtin_amdgcn_mfma_f32_16x16x32_bf16(
            ah[mi], bh[ni], acc[mi][ni], 0, 0, 0);
        acc[mi][ni] = __builtin_amdgcn_mfma_f32_16x16x32_bf16(
            ah[mi], bl[ni], acc[mi][ni], 0, 0, 0);
        acc[mi][ni] = __builtin_amdgcn_mfma_f32_16x16x32_bf16(
            al[mi], bh[ni], acc[mi][ni], 0, 0, 0);
        acc[mi][ni] = __builtin_amdgcn_mfma_f32_16x16x32_bf16(
            al[mi], bl[ni], acc[mi][ni], 0, 0, 0);
      }
    __syncthreads();
  }

  // epilogue: C/D layout col=lane&15, row=(lane>>4)*4+j  [m89-verified]
  const int r0 = m0 + wr * 64 + (lane >> 4) * 4;
  const int c0 = n0 + wc * 64 + (lane & 15);
#pragma unroll
  for (int ni = 0; ni < 4; ++ni) {
    const int col = c0 + ni * 16;
    const float badd = (bias != nullptr) ? bias[col] : 0.f;
#pragma unroll
    for (int mi = 0; mi < 4; ++mi) {
#pragma unroll
      for (int j = 0; j < 4; ++j) {
        const int row = r0 + mi * 16 + j;
        C[(size_t)row * C_ + col] = acc[mi][ni][j] + badd;
      }
    }
  }
}

// ---------------------------------------------------------------------------
// Fused RBF attention, one block per (b,h). Thread i owns query row i.
// K/V staged in LDS in 49-row tiles (whole-wave same-address reads are
// broadcasts -> conflict-free). No-max softmax: logit <= ~0.17 always
// (sqdist >= 0, scale < 0, gelu bias >= -0.17) so exp never overflows;
// softmax shift-invariance => matches reference.
// Output written as bf16 hi/lo (ushort4-vectorized) for the final MFMA GEMM.
// NOTE: no min-waves in launch_bounds — (256,2) would cap VGPR at 128 and
// spill qv[16] (64 regs) + o[64] (64 regs) to scratch.
// ---------------------------------------------------------------------------
#define JT 49

__global__ __launch_bounds__(256) void attn_kernel(
    const float* __restrict__ Q, const float* __restrict__ K,
    const float* __restrict__ V, const float* __restrict__ bias,
    unsigned short* __restrict__ Oh, unsigned short* __restrict__ Ol) {
  __shared__ float Ks[JT][D_];
  __shared__ float Vs[JT][D_];
  __shared__ float k2s[JT];

  const int bh = blockIdx.x;
  const int b = bh / H_;
  const int h = bh % H_;
  const int tid = threadIdx.x;
  const size_t base = (size_t)b * N_TOK * C_ + (size_t)h * D_;

  float4 qv[16];
  float q2 = 0.f;
  if (tid < N_TOK) {
    const float* qrow = Q + base + (size_t)tid * C_;
    float s0 = 0.f, s1 = 0.f, s2 = 0.f, s3 = 0.f;
#pragma unroll
    for (int d4 = 0; d4 < 16; ++d4) {
      qv[d4] = reinterpret_cast<const float4*>(qrow)[d4];
      s0 = fmaf(qv[d4].x, qv[d4].x, s0);
      s1 = fmaf(qv[d4].y, qv[d4].y, s1);
      s2 = fmaf(qv[d4].z, qv[d4].z, s2);
      s3 = fmaf(qv[d4].w, qv[d4].w, s3);
    }
    q2 = (s0 + s1) + (s2 + s3);
  }

  float o[D_];
#pragma unroll
  for (int d = 0; d < D_; ++d) o[d] = 0.f;
  float l = 0.f;

  for (int t = 0; t < 4; ++t) {
    const int j0 = t * JT;
    __syncthreads();  // protect LDS from previous tile's readers
    for (int f = tid; f < JT * 16; f += 256) {
      const int row = f >> 4;
      const int d4 = f & 15;
      const size_t g = base + (size_t)(j0 + row) * C_ + (size_t)(d4 * 4);
      *reinterpret_cast<float4*>(&Ks[row][d4 * 4]) =
          *reinterpret_cast<const float4*>(&K[g]);
      *reinterpret_cast<float4*>(&Vs[row][d4 * 4]) =
          *reinterpret_cast<const float4*>(&V[g]);
    }
    __syncthreads();
    if (tid < JT) {
      float s0 = 0.f, s1 = 0.f, s2 = 0.f, s3 = 0.f;
#pragma unroll
      for (int d4 = 0; d4 < 16; ++d4) {
        const float4 kv = reinterpret_cast<const float4*>(&Ks[tid][0])[d4];
        s0 = fmaf(kv.x, kv.x, s0);
        s1 = fmaf(kv.y, kv.y, s1);
        s2 = fmaf(kv.z, kv.z, s2);
        s3 = fmaf(kv.w, kv.w, s3);
      }
      k2s[tid] = (s0 + s1) + (s2 + s3);
    }
    __syncthreads();

    if (tid < N_TOK) {
      const float* brow =
          bias + (size_t)h * NN_ + (size_t)tid * N_TOK + (size_t)j0;
      for (int jj = 0; jj < JT; ++jj) {
        float p0 = 0.f, p1 = 0.f, p2 = 0.f, p3 = 0.f;
#pragma unroll
        for (int d4 = 0; d4 < 16; ++d4) {
          const float4 kv = reinterpret_cast<const float4*>(&Ks[jj][0])[d4];
          p0 = fmaf(qv[d4].x, kv.x, p0);
          p1 = fmaf(qv[d4].y, kv.y, p1);
          p2 = fmaf(qv[d4].z, kv.z, p2);
          p3 = fmaf(qv[d4].w, kv.w, p3);
        }
        const float dot = (p0 + p1) + (p2 + p3);
        const float sqd = q2 + k2s[jj] - 2.f * dot;
        const float logit = fmaf(sqd, kRbfScale, -brow[jj]);
        const float p = __expf(logit);
        l += p;
#pragma unroll
        for (int d4 = 0; d4 < 16; ++d4) {
          const float4 vv = reinterpret_cast<const float4*>(&Vs[jj][0])[d4];
          o[d4 * 4 + 0] = fmaf(p, vv.x, o[d4 * 4 + 0]);
          o[d4 * 4 + 1] = fmaf(p, vv.y, o[d4 * 4 + 1]);
          o[d4 * 4 + 2] = fmaf(p, vv.z, o[d4 * 4 + 2]);
          o[d4 * 4 + 3] = fmaf(p, vv.w, o[d4 * 4 + 3]);
        }
      }
    }
  }

  if (tid < N_TOK) {
    const float inv = 1.0f / l;
    const size_t orow = base + (size_t)tid * C_;
#pragma unroll
    for (int d4 = 0; d4 < 16; ++d4) {
      const float v0 = o[d4 * 4 + 0] * inv;
      const float v1 = o[d4 * 4 + 1] * inv;
      const float v2 = o[d4 * 4 + 2] * inv;
      const float v3 = o[d4 * 4 + 3] * inv;
      ushort4 hh, ll;
      hh.x = f2b(v0); ll.x = f2b(v0 - b2f(hh.x));
      hh.y = f2b(v1); ll.y = f2b(v1 - b2f(hh.y));
      hh.z = f2b(v2); ll.z = f2b(v2 - b2f(hh.z));
      hh.w = f2b(v3); ll.w = f2b(v3 - b2f(hh.w));
      *reinterpret_cast<ushort4*>(&Oh[orow + d4 * 4]) = hh;
      *reinterpret_cast<ushort4*>(&Ol[orow + d4 * 4]) = ll;
    }
  }
}

// ---------------------------------------------------------------------------
extern "C" void kernel_launch(void* const* d_in, const int* in_sizes, int n_in,
                              void* d_out, int out_size, void* d_ws,
                              size_t ws_size, hipStream_t stream) {
  (void)in_sizes; (void)n_in; (void)out_size; (void)ws_size;

  const float* x         = (const float*)d_in[0];
  const float* Wq        = (const float*)d_in[1];
  const float* Wk        = (const float*)d_in[2];
  const float* Wv        = (const float*)d_in[3];
  const float* rpe_table = (const float*)d_in[4];
  const float* Wp        = (const float*)d_in[5];
  const float* bp        = (const float*)d_in[6];
  const int*   rpe_index = (const int*)d_in[7];
  float* out = (float*)d_out;

  const size_t mc = (size_t)M_ * C_;      // 9.63M elements
  const size_t wtn = (size_t)C_ * C_;     // 589824

  // Workspace (~165 MB): q|k|v fp32 (CONSECUTIVE: gemm z-batch writes
  // q + z*mc), bias fp32, xh|xl bf16 (reused as attn output hi/lo after the
  // V projection — stream order makes this safe), 8 consecutive weight
  // planes (wtq_h is the base: plane(z)_hi = wtq_h + z*2*wtn).
  float* q     = (float*)d_ws;
  float* k     = q + mc;
  float* v     = k + mc;
  float* biasb = v + mc;                              // H*N*N fp32
  unsigned short* xh  = (unsigned short*)(biasb + (size_t)H_ * NN_);
  unsigned short* xl  = xh + mc;
  unsigned short* wtq_h = xl + mc;
  unsigned short* wtp_h = wtq_h + 6 * wtn;            // z=3 plane (hi)
  unsigned short* aoh = xh;  // alias: x splits dead after V projection
  unsigned short* aol = xl;

  bias_gelu_kernel<<<(NN_ + 255) / 256, 256, 0, stream>>>(rpe_table, rpe_index,
                                                          biasb);
  const int n4 = (int)(mc / 4);
  split_x_kernel<<<(n4 + 255) / 256, 256, 0, stream>>>(x, xh, xl, n4);
  transpose_split4_kernel<<<dim3(C_ / 32, C_ / 32, 4), 256, 0, stream>>>(
      Wq, Wk, Wv, Wp, wtq_h);

  // Fused Q,K,V projections: z in {0,1,2} selects weight plane + output.
  gemm_bf16x4_kernel<<<dim3(M_ / 128, C_ / 128, 3), 256, 0, stream>>>(
      xh, xl, wtq_h, q, nullptr);

  attn_kernel<<<B_ * H_, 256, 0, stream>>>(q, k, v, biasb, aoh, aol);

  // Output projection (+bp): single z-plane starting at wtp_h, writes d_out.
  gemm_bf16x4_kernel<<<dim3(M_ / 128, C_ / 128, 1), 256, 0, stream>>>(
      aoh, aol, wtp_h, out, bp);
}